// Round 3
// baseline (140.203 us; speedup 1.0000x reference)
//
#include <hip/hip_runtime.h>
#include <hip/hip_bf16.h>

// Integrate-and-Fire over T=32 timesteps, x: [T, B, N] f32.
// One thread owns 4 consecutive elements of the [B*N] plane; walks t with
// stride BN/4 float4s. Single-buffered bursts of 8 loads -> 8 compute+store.
// Plain (cached) loads/stores to match the 6.3 TB/s copy recipe (m13);
// __launch_bounds__(256,8) targets <=64 VGPR -> 8 waves/SIMD, so per SIMD
// ~64 outstanding 16B loads hide HBM latency.

#define THRESHOLD 1.0f

typedef float f32x4 __attribute__((ext_vector_type(4)));

__global__ __launch_bounds__(256, 8) void if_kernel(const f32x4* __restrict__ x,
                                                    f32x4* __restrict__ out,
                                                    int bn4) {
    const size_t i = (size_t)blockIdx.x * blockDim.x + threadIdx.x;

    const size_t stride = (size_t)bn4;
    const f32x4* xp = x + i;
    f32x4* op = out + i;

    f32x4 mem;
    mem.x = 0.f; mem.y = 0.f; mem.z = 0.f; mem.w = 0.f;

    #pragma unroll
    for (int tc = 0; tc < 4; ++tc) {
        f32x4 cur[8];
        #pragma unroll
        for (int j = 0; j < 8; ++j)
            cur[j] = xp[(size_t)(tc * 8 + j) * stride];

        #pragma unroll
        for (int j = 0; j < 8; ++j) {
            f32x4 spk;
            mem.x += cur[j].x;
            mem.y += cur[j].y;
            mem.z += cur[j].z;
            mem.w += cur[j].w;
            spk.x = (mem.x - THRESHOLD > 0.f) ? 1.f : 0.f;
            spk.y = (mem.y - THRESHOLD > 0.f) ? 1.f : 0.f;
            spk.z = (mem.z - THRESHOLD > 0.f) ? 1.f : 0.f;
            spk.w = (mem.w - THRESHOLD > 0.f) ? 1.f : 0.f;
            mem.x = (spk.x > 0.5f) ? 0.f : mem.x;
            mem.y = (spk.y > 0.5f) ? 0.f : mem.y;
            mem.z = (spk.z > 0.5f) ? 0.f : mem.z;
            mem.w = (spk.w > 0.5f) ? 0.f : mem.w;
            op[(size_t)(tc * 8 + j) * stride] = spk;
        }
    }
}

extern "C" void kernel_launch(void* const* d_in, const int* in_sizes, int n_in,
                              void* d_out, int out_size, void* d_ws, size_t ws_size,
                              hipStream_t stream) {
    const float* x = (const float*)d_in[0];
    float* out = (float*)d_out;

    const int T = 32;
    const int total = in_sizes[0];        // T * B * N
    const int bn = total / T;             // B * N = 2097152
    const int bn4 = bn / 4;               // 524288 float4 columns

    const int block = 256;
    const int grid = (bn4 + block - 1) / block;  // 2048, exact

    if_kernel<<<grid, block, 0, stream>>>((const f32x4*)x, (f32x4*)out, bn4);
}

// Round 4
// 124.138 us; speedup vs baseline: 1.1294x; 1.1294x over previous
//
#include <hip/hip_runtime.h>
#include <hip/hip_bf16.h>

// Integrate-and-Fire over T=32 timesteps, x: [T, B, N] f32.
// One thread owns 4 consecutive floats of the [B*N] plane, walks t at stride
// BN/4 float4s. Limiter analysis (R1-R3): loads-in-flight per SIMD. This
// version keeps 24 16B-loads in flight per wave (3 chunks x 8, rotating
// buffer, fully static indexing) at ~120 VGPR -> 4 waves/SIMD -> ~96
// outstanding loads/SIMD, enough to cover ~1100cy HBM latency at the
// 10 B/cy/CU HBM issue ceiling. No launch_bounds cap (R3: forcing occupancy
// makes the compiler drop the burst buffers, VGPR 24, MLP collapse).

#define THRESHOLD 1.0f

typedef float f32x4 __attribute__((ext_vector_type(4)));

__global__ void if_kernel(const f32x4* __restrict__ x,
                          f32x4* __restrict__ out,
                          int bn4) {
    const size_t i = (size_t)blockIdx.x * blockDim.x + threadIdx.x;
    const size_t stride = (size_t)bn4;
    const f32x4* xp = x + i;
    f32x4* op = out + i;

    f32x4 buf[3][8];

    // Prologue: chunks 0,1,2 -> 24 loads issued back-to-back.
    #pragma unroll
    for (int c = 0; c < 3; ++c) {
        #pragma unroll
        for (int j = 0; j < 8; ++j)
            buf[c][j] = xp[(size_t)(c * 8 + j) * stride];
    }

    f32x4 mem;
    mem.x = 0.f; mem.y = 0.f; mem.z = 0.f; mem.w = 0.f;

    #pragma unroll
    for (int tc = 0; tc < 4; ++tc) {
        const int b = tc % 3;           // compile-time after unroll
        #pragma unroll
        for (int j = 0; j < 8; ++j) {
            f32x4 xv = buf[b][j];
            f32x4 spk;
            mem.x += xv.x;
            mem.y += xv.y;
            mem.z += xv.z;
            mem.w += xv.w;
            spk.x = (mem.x - THRESHOLD > 0.f) ? 1.f : 0.f;
            spk.y = (mem.y - THRESHOLD > 0.f) ? 1.f : 0.f;
            spk.z = (mem.z - THRESHOLD > 0.f) ? 1.f : 0.f;
            spk.w = (mem.w - THRESHOLD > 0.f) ? 1.f : 0.f;
            mem.x = (spk.x > 0.5f) ? 0.f : mem.x;
            mem.y = (spk.y > 0.5f) ? 0.f : mem.y;
            mem.z = (spk.z > 0.5f) ? 0.f : mem.z;
            mem.w = (spk.w > 0.5f) ? 0.f : mem.w;
            op[(size_t)(tc * 8 + j) * stride] = spk;
        }
        // Prefetch chunk tc+3 into the buffer slot just freed (tc==0 only,
        // since there are 4 chunks total and 3 were preloaded).
        if (tc + 3 < 4) {
            #pragma unroll
            for (int j = 0; j < 8; ++j)
                buf[b][j] = xp[(size_t)((tc + 3) * 8 + j) * stride];
        }
    }
}

extern "C" void kernel_launch(void* const* d_in, const int* in_sizes, int n_in,
                              void* d_out, int out_size, void* d_ws, size_t ws_size,
                              hipStream_t stream) {
    const float* x = (const float*)d_in[0];
    float* out = (float*)d_out;

    const int T = 32;
    const int total = in_sizes[0];        // T * B * N
    const int bn = total / T;             // B * N = 2097152
    const int bn4 = bn / 4;               // 524288 float4 columns

    const int block = 256;
    const int grid = bn4 / block;         // 2048, exact (bn4 % block == 0)

    if_kernel<<<grid, block, 0, stream>>>((const f32x4*)x, (f32x4*)out, bn4);
}

// Round 5
// 87.628 us; speedup vs baseline: 1.6000x; 1.4167x over previous
//
#include <hip/hip_runtime.h>
#include <hip/hip_bf16.h>

// Integrate-and-Fire over T=32 timesteps, x: [T, B, N] f32.
// One thread owns 4 consecutive floats of the [B*N] plane, walks t at stride
// BN/4 float4s. R1/R2/R4 established the plateau (~120us) is not MLP-depth,
// issue-rate, or burst-order limited. R3 counters showed FETCH=134MB (half of
// x already L3-resident across replays) while our 268MB/replay write stream
// evicts the rest. This version: CACHED loads (let x live in the 256MiB L3)
// + NONTEMPORAL stores (write-once output must not allocate/evict).
// Burst-of-8 structure, no launch_bounds (R3: forcing occupancy collapses
// the burst buffers to VGPR=24 and MLP dies).

#define THRESHOLD 1.0f

typedef float f32x4 __attribute__((ext_vector_type(4)));

__global__ void if_kernel(const f32x4* __restrict__ x,
                          f32x4* __restrict__ out,
                          int bn4) {
    const size_t i = (size_t)blockIdx.x * blockDim.x + threadIdx.x;
    const size_t stride = (size_t)bn4;
    const f32x4* xp = x + i;
    f32x4* op = out + i;

    f32x4 mem;
    mem.x = 0.f; mem.y = 0.f; mem.z = 0.f; mem.w = 0.f;

    #pragma unroll
    for (int tc = 0; tc < 4; ++tc) {
        f32x4 cur[8];
        #pragma unroll
        for (int j = 0; j < 8; ++j)
            cur[j] = xp[(size_t)(tc * 8 + j) * stride];   // cached read

        #pragma unroll
        for (int j = 0; j < 8; ++j) {
            f32x4 spk;
            mem.x += cur[j].x;
            mem.y += cur[j].y;
            mem.z += cur[j].z;
            mem.w += cur[j].w;
            spk.x = (mem.x - THRESHOLD > 0.f) ? 1.f : 0.f;
            spk.y = (mem.y - THRESHOLD > 0.f) ? 1.f : 0.f;
            spk.z = (mem.z - THRESHOLD > 0.f) ? 1.f : 0.f;
            spk.w = (mem.w - THRESHOLD > 0.f) ? 1.f : 0.f;
            mem.x = (spk.x > 0.5f) ? 0.f : mem.x;
            mem.y = (spk.y > 0.5f) ? 0.f : mem.y;
            mem.z = (spk.z > 0.5f) ? 0.f : mem.z;
            mem.w = (spk.w > 0.5f) ? 0.f : mem.w;
            __builtin_nontemporal_store(spk, op + (size_t)(tc * 8 + j) * stride);
        }
    }
}

extern "C" void kernel_launch(void* const* d_in, const int* in_sizes, int n_in,
                              void* d_out, int out_size, void* d_ws, size_t ws_size,
                              hipStream_t stream) {
    const float* x = (const float*)d_in[0];
    float* out = (float*)d_out;

    const int T = 32;
    const int total = in_sizes[0];        // T * B * N
    const int bn = total / T;             // B * N = 2097152
    const int bn4 = bn / 4;               // 524288 float4 columns

    const int block = 256;
    const int grid = bn4 / block;         // 2048, exact

    if_kernel<<<grid, block, 0, stream>>>((const f32x4*)x, (f32x4*)out, bn4);
}